// Round 2
// baseline (875.557 us; speedup 1.0000x reference)
//
#include <hip/hip_runtime.h>
#include <math.h>

// Problem constants (fixed by the reference)
#define NNODES 262144
#define BATCH  64
#define CD     320          // C*D = 5*64 flattened features per plane
#define NPLANE 3
#define NCHUNK 8            // node-chunks per segment (grid.x)
#define RSLOT  4            // row-slots per block (rows in flight per block-iter)
#define NQ     (CD / 4)     // 80 float4 per row
#define BLK1   (RSLOT * NQ) // 320 threads
#define NEG_BIG (-3.0e38f)

// Uniform binary search: first index with a[i] >= key (batch array is sorted).
// Address is wave-uniform -> compiler emits scalar loads.
__device__ __forceinline__ int lower_bound_dev(const int* __restrict__ a, int n, int key) {
    int lo = 0, hi = n;
    while (lo < hi) {
        int mid = (lo + hi) >> 1;
        if (a[mid] < key) lo = mid + 1; else hi = mid;
    }
    return lo;
}

// Merge online-softmax state (m,d,n) <- (m2,d2,n2).
// Uses exp(-|m-m2|) so -3e38 sentinels never produce inf-inf NaN.
__device__ __forceinline__ void combine_state(float& m, float& d, float& n,
                                              float m2, float d2, float n2) {
    float M  = fmaxf(m, m2);
    float p  = __expf(-fabsf(m - m2));
    bool  ge = (m >= m2);
    float s1 = ge ? 1.0f : p;
    float s2 = ge ? p : 1.0f;
    d = d * s1 + d2 * s2;
    n = n * s1 + n2 * s2;
    m = M;
}

// One online-softmax element update on state (m,d,n).
__device__ __forceinline__ void update_state(float& m, float& d, float& n,
                                             float xv, float tval) {
    float s  = tval * xv;
    float p  = __expf(-fabsf(s - m));   // single exp per element
    bool  gt = (s > m);
    float scale = gt ? p : 1.0f;        // rescale old state
    float e     = gt ? 1.0f : p;        // weight of new elem
    m = fmaxf(m, s);
    d = d * scale + e;
    n = n * scale + e * xv;
}

// Kernel 1: per (plane, segment, chunk) partial online softmax.
// 320 threads: thread = (row-slot r = tid/80, float4-col q = tid%80).
// Each iteration streams RSLOT=4 rows via float4 loads with +1 prefetch.
// part layout: [plane][b][chunk][3(m,d,n)][CD]
__global__ __launch_bounds__(BLK1)
void seg_softmax_partial(const float* __restrict__ m_u, const int* __restrict__ b_u, const float* __restrict__ t_u,
                         const float* __restrict__ m_v, const int* __restrict__ b_v, const float* __restrict__ t_v,
                         const float* __restrict__ m_y, const int* __restrict__ b_y, const float* __restrict__ t_y,
                         float* __restrict__ part)
{
    const int c     = blockIdx.x;   // chunk
    const int bseg  = blockIdx.y;   // segment id
    const int plane = blockIdx.z;

    const float* x; const int* idx; float tval;
    if (plane == 0)      { x = m_u; idx = b_u; tval = t_u[0]; }
    else if (plane == 1) { x = m_v; idx = b_v; tval = t_v[0]; }
    else                 { x = m_y; idx = b_y; tval = t_y[0]; }

    const int start = lower_bound_dev(idx, NNODES, bseg);
    const int end   = lower_bound_dev(idx, NNODES, bseg + 1);

    const int tid = threadIdx.x;
    const int q   = tid % NQ;       // float4 column within row
    const int r   = tid / NQ;       // row-slot

    float m[4], d[4], n[4];
    #pragma unroll
    for (int j = 0; j < 4; ++j) { m[j] = NEG_BIG; d[j] = 0.f; n[j] = 0.f; }

    const int stride = NCHUNK * RSLOT;     // 32 rows per grid-chunk step
    const int i0 = start + c * RSLOT + r;
    const float4* __restrict__ xp = (const float4*)x;

    if (i0 < end) {
        float4 cur = xp[(size_t)i0 * NQ + q];
        for (int i = i0; i < end; i += stride) {
            const int inext  = i + stride;
            const int iclamp = (inext < end) ? inext : (end - 1);  // always-valid prefetch
            float4 nxt = xp[(size_t)iclamp * NQ + q];
            // compute on cur while nxt is in flight
            update_state(m[0], d[0], n[0], cur.x, tval);
            update_state(m[1], d[1], n[1], cur.y, tval);
            update_state(m[2], d[2], n[2], cur.z, tval);
            update_state(m[3], d[3], n[3], cur.w, tval);
            cur = nxt;
        }
    }

    // Reduce RSLOT row-slots -> one state per feature, via LDS (15360 B total).
    __shared__ float sm[RSLOT * CD];
    __shared__ float sd[RSLOT * CD];
    __shared__ float sn[RSLOT * CD];
    const int wbase = r * CD + 4 * q;
    *(float4*)&sm[wbase] = make_float4(m[0], m[1], m[2], m[3]);
    *(float4*)&sd[wbase] = make_float4(d[0], d[1], d[2], d[3]);
    *(float4*)&sn[wbase] = make_float4(n[0], n[1], n[2], n[3]);
    __syncthreads();

    const int f = tid;              // 0..319 feature id
    float M = sm[f], D = sd[f], Nn = sn[f];
    #pragma unroll
    for (int rr = 1; rr < RSLOT; ++rr)
        combine_state(M, D, Nn, sm[rr * CD + f], sd[rr * CD + f], sn[rr * CD + f]);

    size_t base = ((((size_t)plane * BATCH + bseg) * NCHUNK + c) * 3) * CD + f;
    part[base]          = M;
    part[base + CD]     = D;
    part[base + 2 * CD] = Nn;
}

// Kernel 2 (fused): merge NCHUNK partials per (plane,b,f), form feat value,
// multiply into W on the fly, block-reduce to the 3 event logits of batch b.
__global__ __launch_bounds__(CD)
void merge_decode(const float* __restrict__ part, const float* __restrict__ W,
                  const float* __restrict__ bias, float* __restrict__ out)
{
    const int b = blockIdx.x;       // 0..63
    const int f = threadIdx.x;      // 0..319

    float acc0 = 0.f, acc1 = 0.f, acc2 = 0.f;
    #pragma unroll
    for (int p = 0; p < NPLANE; ++p) {
        size_t base = ((((size_t)p * BATCH + b) * NCHUNK) * 3) * CD + f;
        float M = part[base], D = part[base + CD], Nn = part[base + 2 * CD];
        #pragma unroll
        for (int cidx = 1; cidx < NCHUNK; ++cidx) {
            size_t b2 = base + (size_t)cidx * 3 * CD;
            combine_state(M, D, Nn, part[b2], part[b2 + CD], part[b2 + 2 * CD]);
        }
        float fv = (D > 0.f) ? (Nn / D) : 0.f;   // feat[b][p*CD+f]
        acc0 += fv * W[0 * (NPLANE * CD) + p * CD + f];
        acc1 += fv * W[1 * (NPLANE * CD) + p * CD + f];
        acc2 += fv * W[2 * (NPLANE * CD) + p * CD + f];
    }

    // Wave (64-lane) reduce, then cross-wave via LDS.
    #pragma unroll
    for (int off = 32; off > 0; off >>= 1) {
        acc0 += __shfl_down(acc0, off);
        acc1 += __shfl_down(acc1, off);
        acc2 += __shfl_down(acc2, off);
    }
    __shared__ float red[BLK1 / 64][3];  // 5 waves x 3
    const int wave = f >> 6, lane = f & 63;
    if (lane == 0) { red[wave][0] = acc0; red[wave][1] = acc1; red[wave][2] = acc2; }
    __syncthreads();
    if (f < 3) {
        float s = bias[f];
        #pragma unroll
        for (int w = 0; w < CD / 64; ++w) s += red[w][f];
        out[b * 3 + f] = s;
    }
}

extern "C" void kernel_launch(void* const* d_in, const int* in_sizes, int n_in,
                              void* d_out, int out_size, void* d_ws, size_t ws_size,
                              hipStream_t stream)
{
    // setup_inputs() order: m_u, batch_u, t_u, m_v, batch_v, t_v, m_y, batch_y, t_y, W, b
    const float* m_u = (const float*)d_in[0];
    const int*   b_u = (const int*)  d_in[1];
    const float* t_u = (const float*)d_in[2];
    const float* m_v = (const float*)d_in[3];
    const int*   b_v = (const int*)  d_in[4];
    const float* t_v = (const float*)d_in[5];
    const float* m_y = (const float*)d_in[6];
    const int*   b_y = (const int*)  d_in[7];
    const float* t_y = (const float*)d_in[8];
    const float* W   = (const float*)d_in[9];
    const float* bia = (const float*)d_in[10];
    float* out = (float*)d_out;

    // Workspace: partial states [3][64][8][3][320] = 5.9 MB
    float* part = (float*)d_ws;

    dim3 g1(NCHUNK, BATCH, NPLANE), b1(BLK1);
    seg_softmax_partial<<<g1, b1, 0, stream>>>(m_u, b_u, t_u, m_v, b_v, t_v,
                                               m_y, b_y, t_y, part);

    merge_decode<<<BATCH, CD, 0, stream>>>(part, W, bia, out);
}